// Round 2
// baseline (124.473 us; speedup 1.0000x reference)
//
#include <hip/hip_runtime.h>

#define BB 256
#define TT 32
#define DD 256
#define HH 256

// Fully fused QLSTM: one block per batch element.
// Analytic collapse (verified absmax=0.0 in round 1):
//   - hidden state is a scalar per (b,t) broadcast over H (gates are [B,1], c0=h0=0)
//   - qlayer(ang) == cos(rx[0] + ang) * K,  K = (1 + sum_{w>=1} prod_{j<=w} cos(rx[j]))/8
//   - rz params drop out of <Z> entirely
// Phase 1: ax[t][g] = x[b,t,:].W_g[0,:D] + b_g   (per-wave shfl-tree dots)
// Phase 2: 32-step scalar LSTM scan on one lane (all 4 gates in-lane, no shuffles)
// Phase 3: coalesced float4 broadcast into ys[B,T,H] ++ hx[B,H] ++ cx[B,H]

__global__ __launch_bounds__(256) void qlstm_fused(
    const float* __restrict__ x,
    const float* __restrict__ pWf, const float* __restrict__ pbf, const float* __restrict__ prxf,
    const float* __restrict__ pWi, const float* __restrict__ pbi, const float* __restrict__ prxi,
    const float* __restrict__ pWg, const float* __restrict__ pbg, const float* __restrict__ prxg,
    const float* __restrict__ pWo, const float* __restrict__ pbo, const float* __restrict__ prxo,
    float* __restrict__ out)
{
    __shared__ float sAx[TT][4];
    __shared__ float sH[TT];
    __shared__ float sWh[4], sK[4], sRx0[4];
    __shared__ float sHC[2];

    const int tid  = threadIdx.x;
    const int lane = tid & 63;
    const int wave = tid >> 6;
    const int b    = blockIdx.x;

    // W row 0, x-part: float4 per lane (4 KB/gate, L2-hot across all 256 blocks)
    const float4 wf = reinterpret_cast<const float4*>(pWf)[lane];
    const float4 wi = reinterpret_cast<const float4*>(pWi)[lane];
    const float4 wg = reinterpret_cast<const float4*>(pWg)[lane];
    const float4 wo = reinterpret_cast<const float4*>(pWo)[lane];
    const float bf0 = pbf[0], bi0 = pbi[0], bg0 = pbg[0], bo0 = pbo[0];

    // per-wave: wh_gate = sum W_gate[0, D:D+H]  (h uniform over hidden cols)
    {
        const float* Wsel = (wave == 0) ? pWf : (wave == 1) ? pWi : (wave == 2) ? pWg : pWo;
        const float4 hw = reinterpret_cast<const float4*>(Wsel + DD)[lane];
        float s = hw.x + hw.y + hw.z + hw.w;
        #pragma unroll
        for (int off = 32; off > 0; off >>= 1) s += __shfl_down(s, off);
        if (lane == 0) sWh[wave] = s;
    }
    // 4 threads: K and rx0 per gate (Horner over 8 cosines)
    if (tid < 4) {
        const float* rx = (tid == 0) ? prxf : (tid == 1) ? prxi : (tid == 2) ? prxg : prxo;
        float acc = 0.f;
        for (int j = 7; j >= 1; --j) acc = cosf(rx[j]) * (1.f + acc);
        sK[tid]   = (1.f + acc) * 0.125f;
        sRx0[tid] = rx[0];
    }

    // Phase 1: each wave owns 8 timesteps
    #pragma unroll
    for (int k = 0; k < 8; ++k) {
        const int t = wave * 8 + k;
        const float4 xv = reinterpret_cast<const float4*>(x + (b * TT + t) * DD)[lane];
        float sf = xv.x*wf.x + xv.y*wf.y + xv.z*wf.z + xv.w*wf.w;
        float si = xv.x*wi.x + xv.y*wi.y + xv.z*wi.z + xv.w*wi.w;
        float sg = xv.x*wg.x + xv.y*wg.y + xv.z*wg.z + xv.w*wg.w;
        float so = xv.x*wo.x + xv.y*wo.y + xv.z*wo.z + xv.w*wo.w;
        #pragma unroll
        for (int off = 32; off > 0; off >>= 1) {
            sf += __shfl_down(sf, off);
            si += __shfl_down(si, off);
            sg += __shfl_down(sg, off);
            so += __shfl_down(so, off);
        }
        if (lane == 0) {
            sAx[t][0] = sf + bf0;
            sAx[t][1] = si + bi0;
            sAx[t][2] = sg + bg0;
            sAx[t][3] = so + bo0;
        }
    }
    __syncthreads();

    // Phase 2: scalar scan, one lane, all 4 gates in-register (ILP across gates)
    if (tid == 0) {
        const float whf = sWh[0], whi = sWh[1], whg = sWh[2], who = sWh[3];
        const float Kf  = sK[0],  Ki  = sK[1],  Kg  = sK[2],  Ko  = sK[3];
        const float r0f = sRx0[0], r0i = sRx0[1], r0g = sRx0[2], r0o = sRx0[3];
        float h = 0.f, c = 0.f;
        for (int t = 0; t < TT; ++t) {
            const float vf = cosf(r0f + sAx[t][0] + h * whf) * Kf;
            const float vi = cosf(r0i + sAx[t][1] + h * whi) * Ki;
            const float vg = cosf(r0g + sAx[t][2] + h * whg) * Kg;
            const float vo = cosf(r0o + sAx[t][3] + h * who) * Ko;
            const float fv = 1.f / (1.f + expf(-vf));
            const float iv = 1.f / (1.f + expf(-vi));
            const float gv = tanhf(vg);
            const float ov = 1.f / (1.f + expf(-vo));
            c = fv * c + iv * gv;
            h = ov * tanhf(c);
            sH[t] = h;
        }
        sHC[0] = h; sHC[1] = c;
    }
    __syncthreads();

    // Phase 3: broadcast writes. ys: 8 threads/row, 8 float4 each (128B chunks).
    float4* out4 = (float4*)out;
    {
        const int t = tid >> 3, j = tid & 7;
        const float hv = sH[t];
        const float4 h4 = make_float4(hv, hv, hv, hv);
        const int rowb = (b * TT + t) * (HH / 4);
        #pragma unroll
        for (int k = 0; k < 8; ++k) out4[rowb + k * 8 + j] = h4;
    }
    if (tid < 64) {
        const float v = sHC[0];
        out4[BB * TT * (HH / 4) + b * (HH / 4) + tid] = make_float4(v, v, v, v);
    } else if (tid < 128) {
        const float v = sHC[1];
        out4[BB * TT * (HH / 4) + BB * (HH / 4) + b * (HH / 4) + (tid - 64)] = make_float4(v, v, v, v);
    }
}

extern "C" void kernel_launch(void* const* d_in, const int* in_sizes, int n_in,
                              void* d_out, int out_size, void* d_ws, size_t ws_size,
                              hipStream_t stream) {
    // setup_inputs() order: inputs, then per gate n in [f,i,g,o]: Wn, bn, rxn, rzn
    const float* x   = (const float*)d_in[0];
    const float* Wf  = (const float*)d_in[1];
    const float* bf  = (const float*)d_in[2];
    const float* rxf = (const float*)d_in[3];
    const float* Wi  = (const float*)d_in[5];
    const float* bi  = (const float*)d_in[6];
    const float* rxi = (const float*)d_in[7];
    const float* Wg  = (const float*)d_in[9];
    const float* bg  = (const float*)d_in[10];
    const float* rxg = (const float*)d_in[11];
    const float* Wo  = (const float*)d_in[13];
    const float* bo  = (const float*)d_in[14];
    const float* rxo = (const float*)d_in[15];
    // rz params provably drop out of <Z> — unused.

    qlstm_fused<<<BB, 256, 0, stream>>>(x,
                                        Wf, bf, rxf,
                                        Wi, bi, rxi,
                                        Wg, bg, rxg,
                                        Wo, bo, rxo,
                                        (float*)d_out);
}